// Round 26
// baseline (384.235 us; speedup 1.0000x reference)
//
#include <hip/hip_runtime.h>

#define NEG_ATT 0.2f
#define NEG_ACT 0.01f

typedef short s16x8 __attribute__((ext_vector_type(8)));
typedef float f32x4 __attribute__((ext_vector_type(4)));

__device__ __forceinline__ short f2bf_rn(float f) {
  unsigned u = __float_as_uint(f);
  unsigned r = (u + 0x7FFFu + ((u >> 16) & 1u)) >> 16;
  return (short)r;
}
__device__ __forceinline__ float bf2f(short h) {
  return __uint_as_float(((unsigned)(unsigned short)h) << 16);
}

// ---------- convert X fp32 [M][K] -> Xb bf16 [M][2K] (hi cols 0..K-1, lo K..2K-1)
__global__ __launch_bounds__(256) void conv_x(const float* __restrict__ X,
    short* __restrict__ Xb, int M, int K) {
  long long gid = (long long)blockIdx.x * 256 + threadIdx.x;
  long long tot = (long long)M * (K / 4);
  if (gid >= tot) return;
  int row = (int)(gid / (K / 4));
  int c4 = ((int)(gid % (K / 4))) * 4;
  float4 v = *(const float4*)&X[(size_t)row * K + c4];
  short4 hi, lo;
  hi.x = f2bf_rn(v.x); lo.x = f2bf_rn(v.x - bf2f(hi.x));
  hi.y = f2bf_rn(v.y); lo.y = f2bf_rn(v.y - bf2f(hi.y));
  hi.z = f2bf_rn(v.z); lo.z = f2bf_rn(v.z - bf2f(hi.z));
  hi.w = f2bf_rn(v.w); lo.w = f2bf_rn(v.w - bf2f(hi.w));
  *(short4*)&Xb[(size_t)row * 2 * K + c4] = hi;
  *(short4*)&Xb[(size_t)row * 2 * K + K + c4] = lo;
}

// ---------- convert+transpose W fp32 [K][N] -> Wtb bf16 [N][2K]
__global__ __launch_bounds__(256) void conv_w(const float* __restrict__ W,
    short* __restrict__ Wtb, int K, int N) {
  int gid = blockIdx.x * 256 + threadIdx.x;
  if (gid >= K * N) return;
  int k = gid / N, n = gid % N;
  float v = W[(size_t)k * N + n];
  short hi = f2bf_rn(v);
  short lo = f2bf_rn(v - bf2f(hi));
  Wtb[(size_t)n * 2 * K + k] = hi;
  Wtb[(size_t)n * 2 * K + K + k] = lo;
}

// ---------- split-bf16 MFMA GEMM, 128x128 tile, 8 waves (2x4).
// Cb[M][ldc] bf16 = X[M,K] @ W[K,N]. If a_s != nullptr, fuses attention score
// dots: atomicAdd(ssrc[row], sum_col h*a_s[col]) etc. (fp32 h, pre-rounding).
__global__ __launch_bounds__(512) void gemm128(const short* __restrict__ Xb,
    const short* __restrict__ Wtb, short* __restrict__ Cb,
    const float* __restrict__ a_s, const float* __restrict__ a_d,
    float* __restrict__ ssrc, float* __restrict__ sdst,
    int M, int N, int K, int ldc) {
  __shared__ short sA[2][128][40];
  __shared__ short sB[2][128][40];
  const int K2 = 2 * K;
  int tid = threadIdx.x;
  int w = tid >> 6, l = tid & 63;
  int wr = w >> 2, wc = w & 3;          // wave grid 2 (rows) x 4 (cols)
  int bm = blockIdx.y * 128, bn = blockIdx.x * 128;
  int sr = tid >> 2, sq = (tid & 3) * 8;  // staging: row 0..127, k-seg

  f32x4 acc[4][2];
#pragma unroll
  for (int i = 0; i < 4; i++)
#pragma unroll
    for (int j = 0; j < 2; j++) acc[i][j] = (f32x4)0.f;

  int lrow = l & 15, k8 = (l >> 4) * 8;

  for (int k0 = 0; k0 < K; k0 += 32) {
    {
      int g = bm + sr;
      s16x8 hi = (s16x8)0, lo = (s16x8)0;
      if (g < M) {
        hi = *(const s16x8*)&Xb[(size_t)g * K2 + k0 + sq];
        lo = *(const s16x8*)&Xb[(size_t)g * K2 + K + k0 + sq];
      }
      *(s16x8*)&sA[0][sr][sq] = hi;
      *(s16x8*)&sA[1][sr][sq] = lo;
    }
    {
      int g = bn + sr;
      s16x8 hi = (s16x8)0, lo = (s16x8)0;
      if (g < N) {
        hi = *(const s16x8*)&Wtb[(size_t)g * K2 + k0 + sq];
        lo = *(const s16x8*)&Wtb[(size_t)g * K2 + K + k0 + sq];
      }
      *(s16x8*)&sB[0][sr][sq] = hi;
      *(s16x8*)&sB[1][sr][sq] = lo;
    }
    __syncthreads();

    s16x8 aH[4], aL[4], bH[2], bL[2];
#pragma unroll
    for (int mt = 0; mt < 4; mt++) {
      aH[mt] = *(const s16x8*)&sA[0][wr * 64 + mt * 16 + lrow][k8];
      aL[mt] = *(const s16x8*)&sA[1][wr * 64 + mt * 16 + lrow][k8];
    }
#pragma unroll
    for (int nt = 0; nt < 2; nt++) {
      bH[nt] = *(const s16x8*)&sB[0][wc * 32 + nt * 16 + lrow][k8];
      bL[nt] = *(const s16x8*)&sB[1][wc * 32 + nt * 16 + lrow][k8];
    }
#pragma unroll
    for (int mt = 0; mt < 4; mt++)
#pragma unroll
      for (int nt = 0; nt < 2; nt++) {
        acc[mt][nt] = __builtin_amdgcn_mfma_f32_16x16x32_bf16(aH[mt], bH[nt], acc[mt][nt], 0, 0, 0);
        acc[mt][nt] = __builtin_amdgcn_mfma_f32_16x16x32_bf16(aH[mt], bL[nt], acc[mt][nt], 0, 0, 0);
        acc[mt][nt] = __builtin_amdgcn_mfma_f32_16x16x32_bf16(aL[mt], bH[nt], acc[mt][nt], 0, 0, 0);
      }
    __syncthreads();
  }

  int dcol = l & 15, drow4 = (l >> 4) * 4;
#pragma unroll
  for (int mt = 0; mt < 4; mt++) {
    float ps[4] = {0.f, 0.f, 0.f, 0.f}, pd[4] = {0.f, 0.f, 0.f, 0.f};
#pragma unroll
    for (int nt = 0; nt < 2; nt++) {
      int col = bn + wc * 32 + nt * 16 + dcol;
      if (col < N) {
        float asc = 0.f, adc = 0.f;
        if (a_s) { asc = a_s[col]; adc = a_d[col]; }
#pragma unroll
        for (int r = 0; r < 4; r++) {
          int row = bm + wr * 64 + mt * 16 + drow4 + r;
          if (row < M) {
            float v = acc[mt][nt][r];
            Cb[(size_t)row * ldc + col] = f2bf_rn(v);
            ps[r] += v * asc; pd[r] += v * adc;
          }
        }
      }
    }
    if (a_s) {
#pragma unroll
      for (int m = 1; m < 16; m <<= 1) {
#pragma unroll
        for (int r = 0; r < 4; r++) {
          ps[r] += __shfl_xor(ps[r], m);
          pd[r] += __shfl_xor(pd[r], m);
        }
      }
      if ((l & 15) == 0) {
#pragma unroll
        for (int r = 0; r < 4; r++) {
          int row = bm + wr * 64 + mt * 16 + drow4 + r;
          if (row < M) {
            atomicAdd(&ssrc[row], ps[r]);
            atomicAdd(&sdst[row], pd[r]);
          }
        }
      }
    }
  }
}

// ---------- per-node attention scores from bf16 H (row stride ld, F live cols)
__global__ __launch_bounds__(256) void row_dots(const short* __restrict__ Hb,
    const float* __restrict__ a_s, const float* __restrict__ a_d,
    float* __restrict__ s_src, float* __restrict__ s_dst, int Nn, int F, int ld) {
  int node = blockIdx.x * 4 + (threadIdx.x >> 6);
  int lane = threadIdx.x & 63;
  if (node >= Nn) return;
  float ss = 0.f, sd = 0.f;
  for (int c = lane; c < F; c += 64) {
    float h = bf2f(Hb[(size_t)node * ld + c]);
    ss += h * a_s[c];
    sd += h * a_d[c];
  }
#pragma unroll
  for (int off = 32; off > 0; off >>= 1) {
    ss += __shfl_down(ss, off);
    sd += __shfl_down(sd, off);
  }
  if (lane == 0) { s_src[node] = ss; s_dst[node] = sd; }
}

// ---------- CSR build
__global__ __launch_bounds__(256) void deg_hist(const int* __restrict__ dst,
    int* __restrict__ deg, int E) {
  int e = blockIdx.x * 256 + threadIdx.x;
  if (e >= E) return;
  atomicAdd(&deg[dst[e]], 1);
}

// hierarchical scan: A) per-block sums
__global__ __launch_bounds__(256) void scan_partials(const int* __restrict__ deg,
    int* __restrict__ bsum, int N) {
  __shared__ int sdata[256];
  int i = blockIdx.x * 256 + threadIdx.x;
  sdata[threadIdx.x] = (i < N) ? deg[i] : 0;
  __syncthreads();
  for (int off = 128; off > 0; off >>= 1) {
    if (threadIdx.x < off) sdata[threadIdx.x] += sdata[threadIdx.x + off];
    __syncthreads();
  }
  if (threadIdx.x == 0) bsum[blockIdx.x] = sdata[0];
}

// B) exclusive scan of block sums (nb <= 256*k via carry loop)
__global__ __launch_bounds__(256) void scan_offsets(int* __restrict__ bsum, int nb) {
  __shared__ int sdata[256];
  __shared__ int carry;
  int tid = threadIdx.x;
  if (tid == 0) carry = 0;
  __syncthreads();
  for (int base = 0; base < nb; base += 256) {
    int idx = base + tid;
    int v = (idx < nb) ? bsum[idx] : 0;
    sdata[tid] = v;
    __syncthreads();
    for (int off = 1; off < 256; off <<= 1) {
      int t = (tid >= off) ? sdata[tid - off] : 0;
      __syncthreads();
      sdata[tid] += t;
      __syncthreads();
    }
    if (idx < nb) bsum[idx] = carry + sdata[tid] - v;
    __syncthreads();
    if (tid == 255) carry += sdata[255];
    __syncthreads();
  }
}

// C) per-block exclusive scan + block offset -> rowptr; rowptr[N]=E
__global__ __launch_bounds__(256) void scan_final(const int* __restrict__ deg,
    const int* __restrict__ bsum, int* __restrict__ rowptr, int N, int E) {
  __shared__ int sdata[256];
  int i = blockIdx.x * 256 + threadIdx.x;
  int tid = threadIdx.x;
  int v = (i < N) ? deg[i] : 0;
  sdata[tid] = v;
  __syncthreads();
  for (int off = 1; off < 256; off <<= 1) {
    int t = (tid >= off) ? sdata[tid - off] : 0;
    __syncthreads();
    sdata[tid] += t;
    __syncthreads();
  }
  if (i < N) rowptr[i] = bsum[blockIdx.x] + sdata[tid] - v;
  if (blockIdx.x == 0 && tid == 0) rowptr[N] = E;
}

__global__ __launch_bounds__(256) void csr_place(const int* __restrict__ src,
    const int* __restrict__ dst, const int* __restrict__ rowptr,
    int* __restrict__ cnt, int* __restrict__ csr_src, int E) {
  int e = blockIdx.x * 256 + threadIdx.x;
  if (e >= E) return;
  int d = dst[e];
  int pos = rowptr[d] + atomicAdd(&cnt[d], 1);
  csr_src[pos] = src[e];
}

// ---------- fused single-loop softmax+aggregation, F=256: wave per node.
__global__ __launch_bounds__(256) void attn_agg256(const short* __restrict__ Hb,
    const float* __restrict__ ssrc, const float* __restrict__ sdst,
    const int* __restrict__ rowptr, const int* __restrict__ csr_src,
    const float* __restrict__ b, short* __restrict__ outb, int N, float slope) {
  int node = blockIdx.x * 4 + (threadIdx.x >> 6);
  int lane = threadIdx.x & 63;
  if (node >= N) return;
  int r0 = rowptr[node], r1 = rowptr[node + 1];
  float sd = sdst[node];
  int c4 = lane * 4;
  float x0 = 0.f, y0 = 0.f, z0 = 0.f, w0 = 0.f;
  float x1 = 0.f, y1 = 0.f, z1 = 0.f, w1 = 0.f;
  float s = 0.f;
  int i = r0;
  for (; i + 2 <= r1; i += 2) {
    int s0 = csr_src[i], s1 = csr_src[i + 1];
    float v0 = ssrc[s0] + sd; v0 = v0 > 0.f ? v0 : v0 * NEG_ATT;
    float v1 = ssrc[s1] + sd; v1 = v1 > 0.f ? v1 : v1 * NEG_ATT;
    float a0 = expf(v0), a1 = expf(v1);
    s += a0 + a1;
    short4 h0 = *(const short4*)&Hb[(size_t)s0 * 256 + c4];
    short4 h1 = *(const short4*)&Hb[(size_t)s1 * 256 + c4];
    x0 += a0 * bf2f(h0.x); y0 += a0 * bf2f(h0.y);
    z0 += a0 * bf2f(h0.z); w0 += a0 * bf2f(h0.w);
    x1 += a1 * bf2f(h1.x); y1 += a1 * bf2f(h1.y);
    z1 += a1 * bf2f(h1.z); w1 += a1 * bf2f(h1.w);
  }
  if (i < r1) {
    int s0 = csr_src[i];
    float v0 = ssrc[s0] + sd; v0 = v0 > 0.f ? v0 : v0 * NEG_ATT;
    float a0 = expf(v0);
    s += a0;
    short4 h0 = *(const short4*)&Hb[(size_t)s0 * 256 + c4];
    x0 += a0 * bf2f(h0.x); y0 += a0 * bf2f(h0.y);
    z0 += a0 * bf2f(h0.z); w0 += a0 * bf2f(h0.w);
  }
  float inv = 1.f / s;
  float4 bias = *(const float4*)&b[c4];
  float vx = (x0 + x1) * inv + bias.x, vy = (y0 + y1) * inv + bias.y;
  float vz = (z0 + z1) * inv + bias.z, vw = (w0 + w1) * inv + bias.w;
  if (r0 == r1) { vx = bias.x; vy = bias.y; vz = bias.z; vw = bias.w; }
  vx = vx > 0.f ? vx : vx * slope;
  vy = vy > 0.f ? vy : vy * slope;
  vz = vz > 0.f ? vz : vz * slope;
  vw = vw > 0.f ? vw : vw * slope;
  short4 hi, lo;
  hi.x = f2bf_rn(vx); lo.x = f2bf_rn(vx - bf2f(hi.x));
  hi.y = f2bf_rn(vy); lo.y = f2bf_rn(vy - bf2f(hi.y));
  hi.z = f2bf_rn(vz); lo.z = f2bf_rn(vz - bf2f(hi.z));
  hi.w = f2bf_rn(vw); lo.w = f2bf_rn(vw - bf2f(hi.w));
  *(short4*)&outb[(size_t)node * 512 + c4] = hi;
  *(short4*)&outb[(size_t)node * 512 + 256 + c4] = lo;
}

// ---------- fused single-loop softmax+aggregation, layer 3, first-of-graph only
__global__ __launch_bounds__(256) void attn_agg16(const short* __restrict__ Hb,
    const float* __restrict__ ssrc, const float* __restrict__ sdst,
    const int* __restrict__ rowptr, const int* __restrict__ csr_src,
    const float* __restrict__ b, const int* __restrict__ batch,
    float* __restrict__ out, int N, int ld) {
  int node = blockIdx.x * 4 + (threadIdx.x >> 6);
  int lane = threadIdx.x & 63;
  if (node >= N) return;
  if (node != 0 && batch[node] == batch[node - 1]) return;
  int r0 = rowptr[node], r1 = rowptr[node + 1];
  float sd = sdst[node];
  int c = lane & 15, eg = lane >> 4;
  float acc = 0.f, s = 0.f;
  for (int i = r0 + eg; i < r1; i += 4) {
    int sn = csr_src[i];
    float v = ssrc[sn] + sd;
    v = v > 0.f ? v : v * NEG_ATT;
    float a = expf(v);
    s += a;
    acc += a * bf2f(Hb[(size_t)sn * ld + c]);
  }
#pragma unroll
  for (int off = 16; off < 64; off <<= 1) {
    acc += __shfl_xor(acc, off);
    s += __shfl_xor(s, off);
  }
  if (eg == 0) {
    float v = (r0 == r1) ? b[c] : acc / s + b[c];
    out[(size_t)batch[node] * 16 + c] = v;
  }
}

extern "C" void kernel_launch(void* const* d_in, const int* in_sizes, int n_in,
                              void* d_out, int out_size, void* d_ws, size_t ws_size,
                              hipStream_t stream) {
  const float* x   = (const float*)d_in[0];
  const int* src   = (const int*)d_in[1];
  const int* dst   = (const int*)d_in[2];
  const int* batch = (const int*)d_in[3];
  const float* W1 = (const float*)d_in[4];
  const float* as1 = (const float*)d_in[5];
  const float* ad1 = (const float*)d_in[6];
  const float* b1 = (const float*)d_in[7];
  const float* W2 = (const float*)d_in[8];
  const float* as2 = (const float*)d_in[9];
  const float* ad2 = (const float*)d_in[10];
  const float* b2 = (const float*)d_in[11];
  const float* W3 = (const float*)d_in[12];
  const float* as3 = (const float*)d_in[13];
  const float* ad3 = (const float*)d_in[14];
  const float* b3 = (const float*)d_in[15];

  const int N = in_sizes[3];   // 50000 nodes
  const int E = in_sizes[1];   // 800000 edges

  char* ws = (char*)d_ws;
  size_t off = 0;
  auto alloc = [&](size_t bytes) -> void* {
    void* p = ws + off;
    off = (off + bytes + 255) & ~(size_t)255;
    return p;
  };
  short* Hb     = (short*)alloc((size_t)N * 256 * 2);
  short* Xb     = (short*)alloc((size_t)N * 512 * 2);
  float* ssrc   = (float*)alloc((size_t)N * 4);
  float* sdst   = (float*)alloc((size_t)N * 4);
  int* deg      = (int*)alloc((size_t)N * 4);
  int* rowptr   = (int*)alloc((size_t)(N + 1) * 4);
  int* cnt      = (int*)alloc((size_t)N * 4);
  int* csr_src  = (int*)alloc((size_t)E * 4);
  int* bsum     = (int*)alloc((size_t)1024 * 4);
  short* W1tb   = (short*)alloc((size_t)256 * 256 * 2);
  short* W2tb   = (short*)alloc((size_t)256 * 512 * 2);
  short* W3tb   = (short*)alloc((size_t)16 * 512 * 2);
  (void)ws_size;

  dim3 blk(256);
  int eblocks = (E + 255) / 256;
  int nblocks = (N + 255) / 256;
  int g128 = (N + 127) / 128;
  int nb4 = (N + 3) / 4;

  // ---- conversions + CSR build
  conv_w<<<(128 * 256 + 255) / 256, blk, 0, stream>>>(W1, W1tb, 128, 256);
  conv_w<<<(256 * 256 + 255) / 256, blk, 0, stream>>>(W2, W2tb, 256, 256);
  conv_w<<<(256 * 16 + 255) / 256, blk, 0, stream>>>(W3, W3tb, 256, 16);
  conv_x<<<(int)(((long long)N * 32 + 255) / 256), blk, 0, stream>>>(x, Xb, N, 128);
  (void)hipMemsetAsync(deg, 0, (size_t)N * 4, stream);
  deg_hist<<<eblocks, blk, 0, stream>>>(dst, deg, E);
  scan_partials<<<nblocks, blk, 0, stream>>>(deg, bsum, N);
  scan_offsets<<<1, blk, 0, stream>>>(bsum, nblocks);
  scan_final<<<nblocks, blk, 0, stream>>>(deg, bsum, rowptr, N, E);
  (void)hipMemsetAsync(cnt, 0, (size_t)N * 4, stream);
  csr_place<<<eblocks, blk, 0, stream>>>(src, dst, rowptr, cnt, csr_src, E);

  // ---- layer 1: Hb = x @ W1 (bf16) + fused score dots, fused attn+agg -> Xb
  (void)hipMemsetAsync(ssrc, 0, (size_t)N * 4, stream);
  (void)hipMemsetAsync(sdst, 0, (size_t)N * 4, stream);
  gemm128<<<dim3(2, g128), dim3(512), 0, stream>>>(Xb, W1tb, Hb, as1, ad1, ssrc, sdst,
                                                   N, 256, 128, 256);
  attn_agg256<<<nb4, blk, 0, stream>>>(Hb, ssrc, sdst, rowptr, csr_src, b1, Xb, N, NEG_ACT);

  // ---- layer 2
  (void)hipMemsetAsync(ssrc, 0, (size_t)N * 4, stream);
  (void)hipMemsetAsync(sdst, 0, (size_t)N * 4, stream);
  gemm128<<<dim3(2, g128), dim3(512), 0, stream>>>(Xb, W2tb, Hb, as2, ad2, ssrc, sdst,
                                                   N, 256, 256, 256);
  attn_agg256<<<nb4, blk, 0, stream>>>(Hb, ssrc, sdst, rowptr, csr_src, b2, Xb, N, NEG_ACT);

  // ---- layer 3: Hb[:, :16] = h2 @ W3 (N=16, ldc=16), scores, fused attn+agg -> d_out
  gemm128<<<dim3(1, g128), dim3(512), 0, stream>>>(Xb, W3tb, Hb, nullptr, nullptr,
                                                   nullptr, nullptr, N, 16, 256, 16);
  row_dots<<<nb4, blk, 0, stream>>>(Hb, as3, ad3, ssrc, sdst, N, 16, 16);
  attn_agg16<<<nb4, blk, 0, stream>>>(Hb, ssrc, sdst, rowptr, csr_src, b3, batch,
                                      (float*)d_out, N, 16);
}

// Round 27
// 360.973 us; speedup vs baseline: 1.0644x; 1.0644x over previous
//
#include <hip/hip_runtime.h>

#define NEG_ATT 0.2f
#define NEG_ACT 0.01f

typedef short s16x8 __attribute__((ext_vector_type(8)));
typedef float f32x4 __attribute__((ext_vector_type(4)));

__device__ __forceinline__ short f2bf_rn(float f) {
  unsigned u = __float_as_uint(f);
  unsigned r = (u + 0x7FFFu + ((u >> 16) & 1u)) >> 16;
  return (short)r;
}
__device__ __forceinline__ float bf2f(short h) {
  return __uint_as_float(((unsigned)(unsigned short)h) << 16);
}

// ---------- convert X fp32 [M][K] -> Xb bf16 [M][2K] (hi cols 0..K-1, lo K..2K-1)
__global__ __launch_bounds__(256) void conv_x(const float* __restrict__ X,
    short* __restrict__ Xb, int M, int K) {
  long long gid = (long long)blockIdx.x * 256 + threadIdx.x;
  long long tot = (long long)M * (K / 4);
  if (gid >= tot) return;
  int row = (int)(gid / (K / 4));
  int c4 = ((int)(gid % (K / 4))) * 4;
  float4 v = *(const float4*)&X[(size_t)row * K + c4];
  short4 hi, lo;
  hi.x = f2bf_rn(v.x); lo.x = f2bf_rn(v.x - bf2f(hi.x));
  hi.y = f2bf_rn(v.y); lo.y = f2bf_rn(v.y - bf2f(hi.y));
  hi.z = f2bf_rn(v.z); lo.z = f2bf_rn(v.z - bf2f(hi.z));
  hi.w = f2bf_rn(v.w); lo.w = f2bf_rn(v.w - bf2f(hi.w));
  *(short4*)&Xb[(size_t)row * 2 * K + c4] = hi;
  *(short4*)&Xb[(size_t)row * 2 * K + K + c4] = lo;
}

// ---------- convert+transpose W fp32 [K][N] -> Wtb bf16 [N][2K]
__global__ __launch_bounds__(256) void conv_w(const float* __restrict__ W,
    short* __restrict__ Wtb, int K, int N) {
  int gid = blockIdx.x * 256 + threadIdx.x;
  if (gid >= K * N) return;
  int k = gid / N, n = gid % N;
  float v = W[(size_t)k * N + n];
  short hi = f2bf_rn(v);
  short lo = f2bf_rn(v - bf2f(hi));
  Wtb[(size_t)n * 2 * K + k] = hi;
  Wtb[(size_t)n * 2 * K + K + k] = lo;
}

// ---------- split-bf16 MFMA GEMM: Cb[M][ldc] (bf16) = X[M,K] @ W[K,N], ~fp32 internal
__global__ __launch_bounds__(256) void gemm_bf16split(const short* __restrict__ Xb,
    const short* __restrict__ Wtb, short* __restrict__ Cb, int M, int N, int K, int ldc) {
  __shared__ short sA[2][64][40];
  __shared__ short sB[2][64][40];
  const int K2 = 2 * K;
  int tid = threadIdx.x;
  int w = tid >> 6, l = tid & 63;
  int wr = w >> 1, wc = w & 1;
  int bm = blockIdx.y * 64, bn = blockIdx.x * 64;
  int sr = tid >> 2, sq = (tid & 3) * 8;

  f32x4 acc[2][2];
#pragma unroll
  for (int i = 0; i < 2; i++)
#pragma unroll
    for (int j = 0; j < 2; j++) acc[i][j] = (f32x4)0.f;

  int lrow = l & 15, k8 = (l >> 4) * 8;

  for (int k0 = 0; k0 < K; k0 += 32) {
    {
      int g = bm + sr;
      s16x8 hi = (s16x8)0, lo = (s16x8)0;
      if (g < M) {
        hi = *(const s16x8*)&Xb[(size_t)g * K2 + k0 + sq];
        lo = *(const s16x8*)&Xb[(size_t)g * K2 + K + k0 + sq];
      }
      *(s16x8*)&sA[0][sr][sq] = hi;
      *(s16x8*)&sA[1][sr][sq] = lo;
    }
    {
      int g = bn + sr;
      *(s16x8*)&sB[0][sr][sq] = *(const s16x8*)&Wtb[(size_t)g * K2 + k0 + sq];
      *(s16x8*)&sB[1][sr][sq] = *(const s16x8*)&Wtb[(size_t)g * K2 + K + k0 + sq];
    }
    __syncthreads();

    s16x8 aH[2], aL[2], bH[2], bL[2];
#pragma unroll
    for (int mt = 0; mt < 2; mt++) {
      aH[mt] = *(const s16x8*)&sA[0][wr * 32 + mt * 16 + lrow][k8];
      aL[mt] = *(const s16x8*)&sA[1][wr * 32 + mt * 16 + lrow][k8];
    }
#pragma unroll
    for (int nt = 0; nt < 2; nt++) {
      bH[nt] = *(const s16x8*)&sB[0][wc * 32 + nt * 16 + lrow][k8];
      bL[nt] = *(const s16x8*)&sB[1][wc * 32 + nt * 16 + lrow][k8];
    }
#pragma unroll
    for (int mt = 0; mt < 2; mt++)
#pragma unroll
      for (int nt = 0; nt < 2; nt++) {
        acc[mt][nt] = __builtin_amdgcn_mfma_f32_16x16x32_bf16(aH[mt], bH[nt], acc[mt][nt], 0, 0, 0);
        acc[mt][nt] = __builtin_amdgcn_mfma_f32_16x16x32_bf16(aH[mt], bL[nt], acc[mt][nt], 0, 0, 0);
        acc[mt][nt] = __builtin_amdgcn_mfma_f32_16x16x32_bf16(aL[mt], bH[nt], acc[mt][nt], 0, 0, 0);
      }
    __syncthreads();
  }

  int dcol = l & 15, drow4 = (l >> 4) * 4;
#pragma unroll
  for (int mt = 0; mt < 2; mt++)
#pragma unroll
    for (int nt = 0; nt < 2; nt++) {
      int col = bn + wc * 32 + nt * 16 + dcol;
      if (col < N) {
#pragma unroll
        for (int r = 0; r < 4; r++) {
          int row = bm + wr * 32 + mt * 16 + drow4 + r;
          if (row < M) Cb[(size_t)row * ldc + col] = f2bf_rn(acc[mt][nt][r]);
        }
      }
    }
}

// ---------- per-node attention scores from bf16 H (row stride ld, F live cols)
__global__ __launch_bounds__(256) void row_dots(const short* __restrict__ Hb,
    const float* __restrict__ a_s, const float* __restrict__ a_d,
    float* __restrict__ s_src, float* __restrict__ s_dst, int Nn, int F, int ld) {
  int node = blockIdx.x * 4 + (threadIdx.x >> 6);
  int lane = threadIdx.x & 63;
  if (node >= Nn) return;
  float ss = 0.f, sd = 0.f;
  for (int c = lane; c < F; c += 64) {
    float h = bf2f(Hb[(size_t)node * ld + c]);
    ss += h * a_s[c];
    sd += h * a_d[c];
  }
#pragma unroll
  for (int off = 32; off > 0; off >>= 1) {
    ss += __shfl_down(ss, off);
    sd += __shfl_down(sd, off);
  }
  if (lane == 0) { s_src[node] = ss; s_dst[node] = sd; }
}

// ---------- CSR build
__global__ __launch_bounds__(256) void deg_hist(const int* __restrict__ dst,
    int* __restrict__ deg, int E) {
  int e = blockIdx.x * 256 + threadIdx.x;
  if (e >= E) return;
  atomicAdd(&deg[dst[e]], 1);
}

// hierarchical scan: A) per-block sums
__global__ __launch_bounds__(256) void scan_partials(const int* __restrict__ deg,
    int* __restrict__ bsum, int N) {
  __shared__ int sdata[256];
  int i = blockIdx.x * 256 + threadIdx.x;
  sdata[threadIdx.x] = (i < N) ? deg[i] : 0;
  __syncthreads();
  for (int off = 128; off > 0; off >>= 1) {
    if (threadIdx.x < off) sdata[threadIdx.x] += sdata[threadIdx.x + off];
    __syncthreads();
  }
  if (threadIdx.x == 0) bsum[blockIdx.x] = sdata[0];
}

// B) exclusive scan of block sums (nb <= 256*k via carry loop)
__global__ __launch_bounds__(256) void scan_offsets(int* __restrict__ bsum, int nb) {
  __shared__ int sdata[256];
  __shared__ int carry;
  int tid = threadIdx.x;
  if (tid == 0) carry = 0;
  __syncthreads();
  for (int base = 0; base < nb; base += 256) {
    int idx = base + tid;
    int v = (idx < nb) ? bsum[idx] : 0;
    sdata[tid] = v;
    __syncthreads();
    for (int off = 1; off < 256; off <<= 1) {
      int t = (tid >= off) ? sdata[tid - off] : 0;
      __syncthreads();
      sdata[tid] += t;
      __syncthreads();
    }
    if (idx < nb) bsum[idx] = carry + sdata[tid] - v;
    __syncthreads();
    if (tid == 255) carry += sdata[255];
    __syncthreads();
  }
}

// C) per-block exclusive scan + block offset -> rowptr; rowptr[N]=E
__global__ __launch_bounds__(256) void scan_final(const int* __restrict__ deg,
    const int* __restrict__ bsum, int* __restrict__ rowptr, int N, int E) {
  __shared__ int sdata[256];
  int i = blockIdx.x * 256 + threadIdx.x;
  int tid = threadIdx.x;
  int v = (i < N) ? deg[i] : 0;
  sdata[tid] = v;
  __syncthreads();
  for (int off = 1; off < 256; off <<= 1) {
    int t = (tid >= off) ? sdata[tid - off] : 0;
    __syncthreads();
    sdata[tid] += t;
    __syncthreads();
  }
  if (i < N) rowptr[i] = bsum[blockIdx.x] + sdata[tid] - v;
  if (blockIdx.x == 0 && tid == 0) rowptr[N] = E;
}

__global__ __launch_bounds__(256) void csr_place(const int* __restrict__ src,
    const int* __restrict__ dst, const int* __restrict__ rowptr,
    int* __restrict__ cnt, int* __restrict__ csr_src, int E) {
  int e = blockIdx.x * 256 + threadIdx.x;
  if (e >= E) return;
  int d = dst[e];
  int pos = rowptr[d] + atomicAdd(&cnt[d], 1);
  csr_src[pos] = src[e];
}

// ---------- fused softmax+aggregation, F=256: wave per node, two-phase chunks.
// Phase A: each lane computes ONE edge's (src, alpha=exp(score)) -- exp/leaky/
// ssrc-gather once per edge, not wave-redundant. Phase B: broadcast lane j's
// (src, alpha) via __shfl (uniform j -> v_readlane), coalesced 512B/wave row
// gather + 4 cvt + 4 FMA per edge. Denominator via per-lane partials + 1 reduce.
__global__ __launch_bounds__(256) void attn_agg256(const short* __restrict__ Hb,
    const float* __restrict__ ssrc, const float* __restrict__ sdst,
    const int* __restrict__ rowptr, const int* __restrict__ csr_src,
    const float* __restrict__ b, short* __restrict__ outb, int N, float slope) {
  int node = blockIdx.x * 4 + (threadIdx.x >> 6);
  int lane = threadIdx.x & 63;
  if (node >= N) return;
  int r0 = rowptr[node], r1 = rowptr[node + 1];
  float sd = sdst[node];
  int c4 = lane * 4;
  float x0 = 0.f, y0 = 0.f, z0 = 0.f, w0 = 0.f;
  float x1 = 0.f, y1 = 0.f, z1 = 0.f, w1 = 0.f;
  float sl = 0.f;  // per-lane denominator partial
  for (int base = r0; base < r1; base += 64) {
    int nthis = min(64, r1 - base);
    int sn = 0; float a = 0.f;
    if (lane < nthis) {
      sn = csr_src[base + lane];
      float v = ssrc[sn] + sd;
      v = v > 0.f ? v : v * NEG_ATT;
      a = expf(v);
    }
    sl += a;
    int j = 0;
    for (; j + 2 <= nthis; j += 2) {
      int s0 = __shfl(sn, j), s1 = __shfl(sn, j + 1);
      float a0 = __shfl(a, j), a1 = __shfl(a, j + 1);
      short4 h0 = *(const short4*)&Hb[(size_t)s0 * 256 + c4];
      short4 h1 = *(const short4*)&Hb[(size_t)s1 * 256 + c4];
      x0 += a0 * bf2f(h0.x); y0 += a0 * bf2f(h0.y);
      z0 += a0 * bf2f(h0.z); w0 += a0 * bf2f(h0.w);
      x1 += a1 * bf2f(h1.x); y1 += a1 * bf2f(h1.y);
      z1 += a1 * bf2f(h1.z); w1 += a1 * bf2f(h1.w);
    }
    if (j < nthis) {
      int s0 = __shfl(sn, j);
      float a0 = __shfl(a, j);
      short4 h0 = *(const short4*)&Hb[(size_t)s0 * 256 + c4];
      x0 += a0 * bf2f(h0.x); y0 += a0 * bf2f(h0.y);
      z0 += a0 * bf2f(h0.z); w0 += a0 * bf2f(h0.w);
    }
  }
#pragma unroll
  for (int off = 32; off > 0; off >>= 1) sl += __shfl_xor(sl, off);
  float inv = 1.f / sl;
  float4 bias = *(const float4*)&b[c4];
  float vx = (x0 + x1) * inv + bias.x, vy = (y0 + y1) * inv + bias.y;
  float vz = (z0 + z1) * inv + bias.z, vw = (w0 + w1) * inv + bias.w;
  if (r0 == r1) { vx = bias.x; vy = bias.y; vz = bias.z; vw = bias.w; }
  vx = vx > 0.f ? vx : vx * slope;
  vy = vy > 0.f ? vy : vy * slope;
  vz = vz > 0.f ? vz : vz * slope;
  vw = vw > 0.f ? vw : vw * slope;
  short4 hi, lo;
  hi.x = f2bf_rn(vx); lo.x = f2bf_rn(vx - bf2f(hi.x));
  hi.y = f2bf_rn(vy); lo.y = f2bf_rn(vy - bf2f(hi.y));
  hi.z = f2bf_rn(vz); lo.z = f2bf_rn(vz - bf2f(hi.z));
  hi.w = f2bf_rn(vw); lo.w = f2bf_rn(vw - bf2f(hi.w));
  *(short4*)&outb[(size_t)node * 512 + c4] = hi;
  *(short4*)&outb[(size_t)node * 512 + 256 + c4] = lo;
}

// ---------- fused single-loop softmax+aggregation, layer 3, first-of-graph only
__global__ __launch_bounds__(256) void attn_agg16(const short* __restrict__ Hb,
    const float* __restrict__ ssrc, const float* __restrict__ sdst,
    const int* __restrict__ rowptr, const int* __restrict__ csr_src,
    const float* __restrict__ b, const int* __restrict__ batch,
    float* __restrict__ out, int N, int ld) {
  int node = blockIdx.x * 4 + (threadIdx.x >> 6);
  int lane = threadIdx.x & 63;
  if (node >= N) return;
  if (node != 0 && batch[node] == batch[node - 1]) return;
  int r0 = rowptr[node], r1 = rowptr[node + 1];
  float sd = sdst[node];
  int c = lane & 15, eg = lane >> 4;
  float acc = 0.f, s = 0.f;
  for (int i = r0 + eg; i < r1; i += 4) {
    int sn = csr_src[i];
    float v = ssrc[sn] + sd;
    v = v > 0.f ? v : v * NEG_ATT;
    float a = expf(v);
    s += a;
    acc += a * bf2f(Hb[(size_t)sn * ld + c]);
  }
#pragma unroll
  for (int off = 16; off < 64; off <<= 1) {
    acc += __shfl_xor(acc, off);
    s += __shfl_xor(s, off);
  }
  if (eg == 0) {
    float v = (r0 == r1) ? b[c] : acc / s + b[c];
    out[(size_t)batch[node] * 16 + c] = v;
  }
}

extern "C" void kernel_launch(void* const* d_in, const int* in_sizes, int n_in,
                              void* d_out, int out_size, void* d_ws, size_t ws_size,
                              hipStream_t stream) {
  const float* x   = (const float*)d_in[0];
  const int* src   = (const int*)d_in[1];
  const int* dst   = (const int*)d_in[2];
  const int* batch = (const int*)d_in[3];
  const float* W1 = (const float*)d_in[4];
  const float* as1 = (const float*)d_in[5];
  const float* ad1 = (const float*)d_in[6];
  const float* b1 = (const float*)d_in[7];
  const float* W2 = (const float*)d_in[8];
  const float* as2 = (const float*)d_in[9];
  const float* ad2 = (const float*)d_in[10];
  const float* b2 = (const float*)d_in[11];
  const float* W3 = (const float*)d_in[12];
  const float* as3 = (const float*)d_in[13];
  const float* ad3 = (const float*)d_in[14];
  const float* b3 = (const float*)d_in[15];

  const int N = in_sizes[3];   // 50000 nodes
  const int E = in_sizes[1];   // 800000 edges

  char* ws = (char*)d_ws;
  size_t off = 0;
  auto alloc = [&](size_t bytes) -> void* {
    void* p = ws + off;
    off = (off + bytes + 255) & ~(size_t)255;
    return p;
  };
  short* Hb     = (short*)alloc((size_t)N * 256 * 2);
  short* Xb     = (short*)alloc((size_t)N * 512 * 2);
  float* ssrc   = (float*)alloc((size_t)N * 4);
  float* sdst   = (float*)alloc((size_t)N * 4);
  int* deg      = (int*)alloc((size_t)N * 4);
  int* rowptr   = (int*)alloc((size_t)(N + 1) * 4);
  int* cnt      = (int*)alloc((size_t)N * 4);
  int* csr_src  = (int*)alloc((size_t)E * 4);
  int* bsum     = (int*)alloc((size_t)1024 * 4);
  short* W1tb   = (short*)alloc((size_t)256 * 256 * 2);
  short* W2tb   = (short*)alloc((size_t)256 * 512 * 2);
  short* W3tb   = (short*)alloc((size_t)64 * 512 * 2);
  (void)ws_size;

  dim3 blk(256);
  int eblocks = (E + 255) / 256;
  int nblocks = (N + 255) / 256;
  int gblocksY = (N + 63) / 64;
  int nb4 = (N + 3) / 4;

  // ---- conversions + CSR build
  conv_w<<<(128 * 256 + 255) / 256, blk, 0, stream>>>(W1, W1tb, 128, 256);
  conv_w<<<(256 * 256 + 255) / 256, blk, 0, stream>>>(W2, W2tb, 256, 256);
  (void)hipMemsetAsync(W3tb, 0, (size_t)64 * 512 * 2, stream);
  conv_w<<<(256 * 16 + 255) / 256, blk, 0, stream>>>(W3, W3tb, 256, 16);
  conv_x<<<(int)(((long long)N * 32 + 255) / 256), blk, 0, stream>>>(x, Xb, N, 128);
  (void)hipMemsetAsync(deg, 0, (size_t)N * 4, stream);
  deg_hist<<<eblocks, blk, 0, stream>>>(dst, deg, E);
  scan_partials<<<nblocks, blk, 0, stream>>>(deg, bsum, N);
  scan_offsets<<<1, blk, 0, stream>>>(bsum, nblocks);
  scan_final<<<nblocks, blk, 0, stream>>>(deg, bsum, rowptr, N, E);
  (void)hipMemsetAsync(cnt, 0, (size_t)N * 4, stream);
  csr_place<<<eblocks, blk, 0, stream>>>(src, dst, rowptr, cnt, csr_src, E);

  // ---- layer 1: Hb = x @ W1 (bf16), scores, fused attn+agg -> Xb (bf16 split)
  gemm_bf16split<<<dim3(4, gblocksY), blk, 0, stream>>>(Xb, W1tb, Hb, N, 256, 128, 256);
  row_dots<<<nb4, blk, 0, stream>>>(Hb, as1, ad1, ssrc, sdst, N, 256, 256);
  attn_agg256<<<nb4, blk, 0, stream>>>(Hb, ssrc, sdst, rowptr, csr_src, b1, Xb, N, NEG_ACT);

  // ---- layer 2
  gemm_bf16split<<<dim3(4, gblocksY), blk, 0, stream>>>(Xb, W2tb, Hb, N, 256, 256, 256);
  row_dots<<<nb4, blk, 0, stream>>>(Hb, as2, ad2, ssrc, sdst, N, 256, 256);
  attn_agg256<<<nb4, blk, 0, stream>>>(Hb, ssrc, sdst, rowptr, csr_src, b2, Xb, N, NEG_ACT);

  // ---- layer 3: Hb[:, :64] = h2 @ W3 (padded N=64), scores, fused attn+agg -> d_out
  gemm_bf16split<<<dim3(1, gblocksY), blk, 0, stream>>>(Xb, W3tb, Hb, N, 64, 256, 64);
  row_dots<<<nb4, blk, 0, stream>>>(Hb, as3, ad3, ssrc, sdst, N, 16, 64);
  attn_agg16<<<nb4, blk, 0, stream>>>(Hb, ssrc, sdst, rowptr, csr_src, b3, batch,
                                      (float*)d_out, N, 64);
}